// Round 3
// baseline (215.207 us; speedup 1.0000x reference)
//
#include <hip/hip_runtime.h>

#define C_DIM 28
#define HALF 14
#define HW 65536   // 256*256
#define THREADS 256
#define GRID 4096  // 4096*256 = 16*65536 pixels, one per thread

namespace {

constexpr double K_PI = 3.14159265358979323846;

constexpr double cos_taylor(double u) {
    double u2 = u * u;
    double term = 1.0, sum = 1.0;
    for (int i = 1; i <= 12; ++i) {
        term *= -u2 / (double)((2 * i - 1) * (2 * i));
        sum += term;
    }
    return sum;
}

// cos(pi * t / 56), exact integer range reduction (period 112).
constexpr double cos_pi_over56(int t) {
    t %= 112;
    if (t < 0) t += 112;
    double sign = 1.0;
    if (t > 56) t = 112 - t;
    if (t > 28) { t = 56 - t; sign = -1.0; }
    return sign * cos_taylor(K_PI * (double)t / 56.0);
}

// Symmetry-split tables.
//   D[k][n] = 2 cos(pi (2n+1) k / 56),  D[k][27-n] = (-1)^k D[k][n]
//   Dinv[n][k] = cos(pi (2n+1) k / 56) * (k==0 ? .5 : 1)/28,  Dinv[27-n][k] = (-1)^k Dinv[n][k]
// Forward with e[j]=x[j]+x[27-j], f[j]=x[j]-x[27-j]:
//   xd[2m]   = sum_j De[m][j] e[j],   De[m][j] = D[2m][j]
//   xd[2m+1] = sum_j Do[m][j] f[j],   Do[m][j] = D[2m+1][j]
// Inverse with E[n]=sum_m Ge[n][m] y[2m], O[n]=sum_m Go[n][m] y[2m+1]:
//   o[n] = E[n]+O[n],  o[27-n] = E[n]-O[n]
struct Tables {
    float De[HALF][HALF], Do[HALF][HALF];
    float Ge[HALF][HALF], Go[HALF][HALF];
};

constexpr Tables make_tables() {
    Tables t{};
    for (int m = 0; m < HALF; ++m)
        for (int j = 0; j < HALF; ++j) {
            t.De[m][j] = (float)(2.0 * cos_pi_over56((2 * j + 1) * (2 * m)));
            t.Do[m][j] = (float)(2.0 * cos_pi_over56((2 * j + 1) * (2 * m + 1)));
        }
    for (int n = 0; n < HALF; ++n)
        for (int m = 0; m < HALF; ++m) {
            int ke = 2 * m, ko = 2 * m + 1;
            double se = ((ke == 0) ? 0.5 : 1.0) / (double)C_DIM;
            double so = 1.0 / (double)C_DIM;
            t.Ge[n][m] = (float)(cos_pi_over56((2 * n + 1) * ke) * se);
            t.Go[n][m] = (float)(cos_pi_over56((2 * n + 1) * ko) * so);
        }
    return t;
}

constexpr Tables TBL = make_tables();

} // namespace

// One thread = one pixel. launch_bounds(256,4): VGPR cap 128 so the compiler
// keeps the full ~96-value live set in registers (R1/R2 allocated 40-52 ->
// serialized loads / defeated pipelining).
__global__ __launch_bounds__(256, 4) void spedct_kernel(
    const float* __restrict__ x,
    const float* __restrict__ w,
    float* __restrict__ out) {

    const int p  = blockIdx.x * THREADS + threadIdx.x;
    const int b  = p >> 16;
    const int hw = p & (HW - 1);

    const float* xp = x + (size_t)b * (C_DIM * HW) + hw;

    // All 28 channel loads issued up front (independent; one waitcnt).
    float xv[C_DIM];
#pragma unroll
    for (int n = 0; n < C_DIM; ++n) xv[n] = xp[(size_t)n * HW];

    // Weight row: 28 contiguous floats (112 B, 16B-aligned) -> 7x float4.
    float wv[C_DIM];
    const float4* wp4 = (const float4*)(w + (size_t)hw * C_DIM);
#pragma unroll
    for (int i = 0; i < 7; ++i) {
        float4 v = wp4[i];
        wv[4 * i + 0] = v.x; wv[4 * i + 1] = v.y;
        wv[4 * i + 2] = v.z; wv[4 * i + 3] = v.w;
    }

    // Butterfly.
    float e[HALF], f[HALF];
#pragma unroll
    for (int j = 0; j < HALF; ++j) {
        e[j] = xv[j] + xv[27 - j];
        f[j] = xv[j] - xv[27 - j];
    }

    // Forward DCT, even/odd halves: 2 x 14x14 FMA, 28 independent chains.
    float ye[HALF], yo[HALF];
#pragma unroll
    for (int m = 0; m < HALF; ++m) {
        ye[m] = TBL.De[m][0] * e[0];
        yo[m] = TBL.Do[m][0] * f[0];
    }
#pragma unroll
    for (int j = 1; j < HALF; ++j) {
        const float ej = e[j], fj = f[j];
#pragma unroll
        for (int m = 0; m < HALF; ++m) {
            ye[m] = fmaf(TBL.De[m][j], ej, ye[m]);
            yo[m] = fmaf(TBL.Do[m][j], fj, yo[m]);
        }
    }

    // Spectral filter folds into even/odd halves.
#pragma unroll
    for (int m = 0; m < HALF; ++m) {
        ye[m] *= wv[2 * m];
        yo[m] *= wv[2 * m + 1];
    }

    // Inverse DCT, even/odd: E[n], O[n], 28 independent chains.
    float E[HALF], O[HALF];
#pragma unroll
    for (int n = 0; n < HALF; ++n) {
        E[n] = TBL.Ge[n][0] * ye[0];
        O[n] = TBL.Go[n][0] * yo[0];
    }
#pragma unroll
    for (int m = 1; m < HALF; ++m) {
        const float ym = ye[m], zm = yo[m];
#pragma unroll
        for (int n = 0; n < HALF; ++n) {
            E[n] = fmaf(TBL.Ge[n][m], ym, E[n]);
            O[n] = fmaf(TBL.Go[n][m], zm, O[n]);
        }
    }

    // Recombine + coalesced stores (nontemporal: out never re-read).
    float* op = out + (size_t)b * (C_DIM * HW) + hw;
#pragma unroll
    for (int n = 0; n < HALF; ++n) {
        __builtin_nontemporal_store(E[n] + O[n], &op[(size_t)n * HW]);
        __builtin_nontemporal_store(E[n] - O[n], &op[(size_t)(27 - n) * HW]);
    }
}

extern "C" void kernel_launch(void* const* d_in, const int* in_sizes, int n_in,
                              void* d_out, int out_size, void* d_ws, size_t ws_size,
                              hipStream_t stream) {
    const float* x = (const float*)d_in[0];   // [16,28,256,256]
    const float* w = (const float*)d_in[1];   // [256,256,28]
    float* out = (float*)d_out;               // [16,28,256,256]

    spedct_kernel<<<dim3(GRID), dim3(THREADS), 0, stream>>>(x, w, out);
}